// Round 8
// baseline (309.342 us; speedup 1.0000x reference)
//
#include <hip/hip_runtime.h>
#include <math.h>

constexpr float NEG_SLOPE = 0.2f;
constexpr float LN_EPS = 1e-5f;

typedef __attribute__((ext_vector_type(8))) short short8;   // bf16x8 MFMA frag
typedef __attribute__((ext_vector_type(4))) float f32x4;    // MFMA acc

__device__ inline ushort f2bf(float f) {        // fp32 -> bf16 RTN-even
    uint u = __float_as_uint(f);
    u += 0x7fffu + ((u >> 16) & 1u);
    return (ushort)(u >> 16);
}
__device__ inline float bf_lo(uint u) { return __uint_as_float(u << 16); }
__device__ inline float bf_hi(uint u) { return __uint_as_float(u & 0xffff0000u); }

// order-preserving float<->uint key for atomicMax on floats
__device__ inline uint fkey(float f) {
    uint u = __float_as_uint(f);
    return (u & 0x80000000u) ? ~u : (u | 0x80000000u);
}
__device__ inline float funkey(uint k) {
    uint u = (k & 0x80000000u) ? (k ^ 0x80000000u) : ~k;
    return __uint_as_float(u);
}

__device__ inline float pick4(float4 v, int h) {
    float r = v.x;
    r = (h == 1) ? v.y : r;
    r = (h == 2) ? v.z : r;
    r = (h == 3) ? v.w : r;
    return r;
}

__device__ inline void fma8(const uint4& u, float q, float acc[8]) {
    acc[0] = fmaf(q, bf_lo(u.x), acc[0]);
    acc[1] = fmaf(q, bf_hi(u.x), acc[1]);
    acc[2] = fmaf(q, bf_lo(u.y), acc[2]);
    acc[3] = fmaf(q, bf_hi(u.y), acc[3]);
    acc[4] = fmaf(q, bf_lo(u.z), acc[4]);
    acc[5] = fmaf(q, bf_hi(u.z), acc[5]);
    acc[6] = fmaf(q, bf_lo(u.w), acc[6]);
    acc[7] = fmaf(q, bf_hi(u.w), acc[7]);
}

// ---------------- fused dtype conversion pre-pass ----------------

__global__ void k_cvt_all(const float* __restrict__ x,
                          const float* __restrict__ W0,
                          const float* __restrict__ W1,
                          ushort* __restrict__ Xb,
                          ushort* __restrict__ Wt0,
                          ushort* __restrict__ Wt1, int N) {
    int i = blockIdx.x * blockDim.x + threadIdx.x;
    const int nx = N * 8;
    if (i < nx) {
        float4 a = *reinterpret_cast<const float4*>(x + (size_t)i * 8);
        float4 b = *reinterpret_cast<const float4*>(x + (size_t)i * 8 + 4);
        ushort u[8] = {f2bf(a.x), f2bf(a.y), f2bf(a.z), f2bf(a.w),
                       f2bf(b.x), f2bf(b.y), f2bf(b.z), f2bf(b.w)};
        *reinterpret_cast<uint4*>(Xb + (size_t)i * 8) = *reinterpret_cast<const uint4*>(u);
        return;
    }
    i -= nx;
    if (i < 64 * 256) {
        int k = i >> 8, c = i & 255;
        Wt0[(size_t)c * 64 + k] = f2bf(W0[i]);
        return;
    }
    i -= 64 * 256;
    if (i < 256 * 256) {
        int k = i >> 8, c = i & 255;
        Wt1[(size_t)c * 256 + k] = f2bf(W1[i]);
    }
}

// ---------------- CSR build ----------------

__global__ void k_hist(const int* __restrict__ ei, int E, int N, int* __restrict__ cnt) {
    int i = blockIdx.x * blockDim.x + threadIdx.x;
    if (i >= E + N) return;
    int dst = (i < E) ? ei[E + i] : (i - E);
    atomicAdd(&cnt[dst], 1);
}

__global__ __launch_bounds__(1024) void k_scan1(const int* __restrict__ cnt,
                                                int* __restrict__ offs,
                                                int* __restrict__ bsum, int n) {
    __shared__ int wsum[16];
    const int lane = threadIdx.x & 63;
    const int w = threadIdx.x >> 6;
    int i = blockIdx.x * 1024 + threadIdx.x;
    int v = (i < n) ? cnt[i] : 0;
#pragma unroll
    for (int off = 1; off < 64; off <<= 1) {
        int u = __shfl_up(v, off);
        if (lane >= off) v += u;
    }
    if (lane == 63) wsum[w] = v;
    __syncthreads();
    if (w == 0) {
        int x = (lane < 16) ? wsum[lane] : 0;
#pragma unroll
        for (int off = 1; off < 16; off <<= 1) {
            int u = __shfl_up(x, off);
            if (lane >= off) x += u;
        }
        if (lane < 16) wsum[lane] = x;
    }
    __syncthreads();
    v += (w > 0) ? wsum[w - 1] : 0;
    if (i < n) offs[i + 1] = v;
    if (threadIdx.x == 1023) bsum[blockIdx.x] = v;
}

__global__ __launch_bounds__(1024) void k_scan2(const int* __restrict__ bsum,
                                                int* __restrict__ bcarry, int nb) {
    __shared__ int wsum[16];
    const int lane = threadIdx.x & 63;
    const int w = threadIdx.x >> 6;
    int v0 = ((int)threadIdx.x < nb) ? bsum[threadIdx.x] : 0;
    int v = v0;
#pragma unroll
    for (int off = 1; off < 64; off <<= 1) {
        int u = __shfl_up(v, off);
        if (lane >= off) v += u;
    }
    if (lane == 63) wsum[w] = v;
    __syncthreads();
    if (w == 0) {
        int x = (lane < 16) ? wsum[lane] : 0;
#pragma unroll
        for (int off = 1; off < 16; off <<= 1) {
            int u = __shfl_up(x, off);
            if (lane >= off) x += u;
        }
        if (lane < 16) wsum[lane] = x;
    }
    __syncthreads();
    v += (w > 0) ? wsum[w - 1] : 0;
    if ((int)threadIdx.x < nb) bcarry[threadIdx.x] = v - v0;
}

__global__ void k_scan3(int* __restrict__ offs, const int* __restrict__ bcarry,
                        int* __restrict__ cursor, int n) {
    int i = blockIdx.x * blockDim.x + threadIdx.x;
    if (i == 0) { offs[0] = 0; cursor[0] = 0; }
    if (i < n) {
        int v = offs[i + 1] + bcarry[i >> 10];
        offs[i + 1] = v;
        if (i + 1 < n) cursor[i + 1] = v;
    }
}

__global__ void k_scatter(const int* __restrict__ ei, int E, int N,
                          int* __restrict__ cursor, int* __restrict__ csr) {
    int i = blockIdx.x * blockDim.x + threadIdx.x;
    if (i >= E + N) return;
    int src, dst;
    if (i < E) { src = ei[i]; dst = ei[E + i]; }
    else       { src = i - E; dst = i - E; }
    int pos = atomicAdd(&cursor[dst], 1);
    csr[pos] = src;
}

// ---------------- MFMA GEMM: h = Xb * W  (+ fused s,t scores + s-max) --------
// Block = 4 waves, owns one 64-col slice x rbpc 64-row blocks; B in registers.
// XCD-aware mapping; h staged in padded LDS, stored as full 128B row-chunks.
// Also produces gkey[slice] = atomicMax key of max s over all rows (for the
// global-max softmax bound in the aggregation kernel).

template <int K>
__global__ __launch_bounds__(256, 2) void k_gemm_mfma(
    const ushort* __restrict__ Xb, const ushort* __restrict__ Wt,
    const float* __restrict__ a_s, const float* __restrict__ a_d,
    ushort* __restrict__ h, float* __restrict__ s, float* __restrict__ t,
    uint* __restrict__ gkey, int N, int nrb, int cpx, int rbpc)
{
    constexpr int KC = K / 32;
    __shared__ ushort hstage[4][16][72];   // padded: row stride 144B
    __shared__ float wmax[4];

    const int tid = threadIdx.x;
    const int w = tid >> 6;
    const int l = tid & 63;
    const int lr = l & 15;
    const int lk = l >> 4;

    const int bid = blockIdx.x;
    const int xcd = bid & 7;
    const int j = bid >> 3;
    const int slice = j & 3;
    const int chunk = xcd * cpx + (j >> 2);
    const int rb0 = chunk * rbpc;
    const int rb1 = min(rb0 + rbpc, nrb);

    short8 b[4][KC];
#pragma unroll
    for (int ct = 0; ct < 4; ++ct) {
        const ushort* wp = Wt + (size_t)(slice * 64 + ct * 16 + lr) * K + lk * 8;
#pragma unroll
        for (int kc = 0; kc < KC; ++kc)
            b[ct][kc] = *reinterpret_cast<const short8*>(wp + kc * 32);
    }

    float asv[4], adv[4];
#pragma unroll
    for (int ct = 0; ct < 4; ++ct) {
        asv[ct] = a_s[slice * 64 + ct * 16 + lr];
        adv[ct] = a_d[slice * 64 + ct * 16 + lr];
    }

    float blockmax = -1e30f;

    for (int rb = rb0; rb < rb1; ++rb) {
        const int row0 = rb * 64 + w * 16;

        int arow = row0 + lr;
        arow = (arow < N) ? arow : (N - 1);
        const ushort* xp = Xb + (size_t)arow * K + lk * 8;
        short8 a[KC];
#pragma unroll
        for (int kc = 0; kc < KC; ++kc)
            a[kc] = *reinterpret_cast<const short8*>(xp + kc * 32);

        f32x4 acc[4];
#pragma unroll
        for (int ct = 0; ct < 4; ++ct) acc[ct] = (f32x4){0.f, 0.f, 0.f, 0.f};
#pragma unroll
        for (int ct = 0; ct < 4; ++ct)
#pragma unroll
            for (int kc = 0; kc < KC; ++kc)
                acc[ct] = __builtin_amdgcn_mfma_f32_16x16x32_bf16(a[kc], b[ct][kc], acc[ct], 0, 0, 0);

        // fused s,t scores
        float ps[4] = {0.f, 0.f, 0.f, 0.f}, pt[4] = {0.f, 0.f, 0.f, 0.f};
#pragma unroll
        for (int jj = 0; jj < 4; ++jj) {
#pragma unroll
            for (int ct = 0; ct < 4; ++ct) {
                float v = acc[ct][jj];
                ps[jj] = fmaf(v, asv[ct], ps[jj]);
                pt[jj] = fmaf(v, adv[ct], pt[jj]);
            }
        }
#pragma unroll
        for (int jj = 0; jj < 4; ++jj) {
#pragma unroll
            for (int o = 1; o < 16; o <<= 1) {
                ps[jj] += __shfl_xor(ps[jj], o);
                pt[jj] += __shfl_xor(pt[jj], o);
            }
        }
        if (lr == 0) {
#pragma unroll
            for (int jj = 0; jj < 4; ++jj) {
                int row = row0 + lk * 4 + jj;
                if (row < N) {
                    s[(size_t)row * 4 + slice] = ps[jj];
                    t[(size_t)row * 4 + slice] = pt[jj];
                }
            }
        }
        // track block max of s (padding rows are clones of row N-1: harmless)
        float mx = fmaxf(fmaxf(ps[0], ps[1]), fmaxf(ps[2], ps[3]));
        mx = fmaxf(mx, __shfl_xor(mx, 16));
        mx = fmaxf(mx, __shfl_xor(mx, 32));
        blockmax = fmaxf(blockmax, mx);

        // stage output tile in LDS (per-wave private), then coalesced store
#pragma unroll
        for (int ct = 0; ct < 4; ++ct)
#pragma unroll
            for (int jj = 0; jj < 4; ++jj)
                hstage[w][lk * 4 + jj][ct * 16 + lr] = f2bf(acc[ct][jj]);
#pragma unroll
        for (int hf = 0; hf < 2; ++hf) {
            int r = (l >> 3) + hf * 8;
            int ch = l & 7;
            int grow = rb * 64 + w * 16 + r;
            uint4 v = *reinterpret_cast<const uint4*>(&hstage[w][r][ch * 8]);
            if (grow < N)
                *reinterpret_cast<uint4*>(h + (size_t)grow * 256 + slice * 64 + ch * 8) = v;
        }
    }

    if (l == 0) wmax[w] = blockmax;
    __syncthreads();
    if (tid == 0) {
        float m = fmaxf(fmaxf(wmax[0], wmax[1]), fmaxf(wmax[2], wmax[3]));
        atomicMax(&gkey[slice], fkey(m));
    }
}

// ---------------- aggregation (+ bias + LayerNorm + ELU) ----------------
// TWO nodes per wave: 32 lanes per node, lane owns 8 channels (16B bf16).
// GLOBAL-MAX softmax: M̂ = LReLU(s_gmax + t) >= true max (LReLU monotone),
// so p = exp(e - M̂) needs no per-chunk max reduction or rescaling ->
// one-pass stream; next chunk's csr/s loads prefetch under current gather.

template <bool FUSE_W2>
__global__ __launch_bounds__(256) void k_agg_ln_elu(
    const int* __restrict__ offs, const int* __restrict__ csr,
    const float* __restrict__ s, const float* __restrict__ t,
    const ushort* __restrict__ h, const uint* __restrict__ gkey,
    const float* __restrict__ bias,
    const float* __restrict__ lng, const float* __restrict__ lnb,
    ushort* __restrict__ Y, const float* __restrict__ W2,
    float* __restrict__ h2, int N)
{
    __shared__ float p_s[4][2][2][32][4];   // [wid][half][buf][slot][head]
    __shared__ int off_s[4][2][2][32];

    const int tid = threadIdx.x;
    const int wid = tid >> 6;
    const int lane = tid & 63;
    const int half = lane >> 5;
    const int lh = lane & 31;
    const int n = blockIdx.x * 8 + wid * 2 + half;
    if (n >= N) return;
    const int head = lh >> 3;
    const int c0 = lh * 8;

    const float4 t4 = *reinterpret_cast<const float4*>(t + (size_t)n * 4);
    uint4 gk4 = *reinterpret_cast<const uint4*>(gkey);
    float4 Mh;
    {
        float mx;
        mx = funkey(gk4.x) + t4.x; Mh.x = fmaxf(mx, NEG_SLOPE * mx);
        mx = funkey(gk4.y) + t4.y; Mh.y = fmaxf(mx, NEG_SLOPE * mx);
        mx = funkey(gk4.z) + t4.z; Mh.z = fmaxf(mx, NEG_SLOPE * mx);
        mx = funkey(gk4.w) + t4.w; Mh.w = fmaxf(mx, NEG_SLOPE * mx);
    }
    const int beg = offs[n], end = offs[n + 1];

    float4 den4 = make_float4(0.f, 0.f, 0.f, 0.f);
    float acc[8] = {0.f, 0.f, 0.f, 0.f, 0.f, 0.f, 0.f, 0.f};

    const char* hb = reinterpret_cast<const char*>(h) + lh * 16;
    float* pp = &p_s[wid][half][0][0][0];
    int* op = &off_s[wid][half][0][0];

    // preload chunk 0
    int base = beg;
    int cnt = min(32, end - base);
    int src = 0;
    float4 sv = make_float4(0.f, 0.f, 0.f, 0.f);
    if (lh < cnt) {
        src = csr[base + lh];
        sv = *reinterpret_cast<const float4*>(s + (size_t)src * 4);
    }
    int buf = 0;

    while (base < end) {
        // p for current chunk (no cross-lane dependency)
        float4 p4 = make_float4(0.f, 0.f, 0.f, 0.f);
        if (lh < cnt) {
            float ex = sv.x + t4.x; ex = fmaxf(ex, NEG_SLOPE * ex);
            float ey = sv.y + t4.y; ey = fmaxf(ey, NEG_SLOPE * ey);
            float ez = sv.z + t4.z; ez = fmaxf(ez, NEG_SLOPE * ez);
            float ew = sv.w + t4.w; ew = fmaxf(ew, NEG_SLOPE * ew);
            p4.x = __expf(ex - Mh.x);
            p4.y = __expf(ey - Mh.y);
            p4.z = __expf(ez - Mh.z);
            p4.w = __expf(ew - Mh.w);
        }
        den4.x += p4.x; den4.y += p4.y; den4.z += p4.z; den4.w += p4.w;

        *reinterpret_cast<float4*>(pp + buf * 128 + lh * 4) = p4;
        op[buf * 32 + lh] = src << 9;
        asm volatile("s_waitcnt lgkmcnt(0)" ::: "memory");

        // prefetch next chunk's csr + s (overlaps with the gather below)
        int nbase = base + 32;
        int ncnt = min(32, end - nbase);
        int nsrc = 0;
        float4 nsv = make_float4(0.f, 0.f, 0.f, 0.f);
        if (nbase < end && lh < ncnt) {
            nsrc = csr[nbase + lh];
            nsv = *reinterpret_cast<const float4*>(s + (size_t)nsrc * 4);
        }

        // gather, 8 rows in flight (pad slots have p == 0)
        const float* ppb = pp + buf * 128;
        const int* opb = op + buf * 32;
        for (int j0 = 0; j0 < cnt; j0 += 8) {
            uint4 u[8];
            float q[8];
#pragma unroll
            for (int k = 0; k < 8; ++k) {
                q[k] = ppb[(j0 + k) * 4 + head];
                u[k] = *reinterpret_cast<const uint4*>(hb + opb[j0 + k]);
            }
#pragma unroll
            for (int k = 0; k < 8; ++k) fma8(u[k], q[k], acc);
        }

        base = nbase; cnt = ncnt; src = nsrc; sv = nsv; buf ^= 1;
    }

    float4 dsum = den4;
#pragma unroll
    for (int off = 1; off < 32; off <<= 1) {
        dsum.x += __shfl_xor(dsum.x, off);
        dsum.y += __shfl_xor(dsum.y, off);
        dsum.z += __shfl_xor(dsum.z, off);
        dsum.w += __shfl_xor(dsum.w, off);
    }
    const float inv = 1.0f / pick4(dsum, head);
    float4 bv0 = *reinterpret_cast<const float4*>(bias + c0);
    float4 bv1 = *reinterpret_cast<const float4*>(bias + c0 + 4);
    float v[8];
    v[0] = acc[0] * inv + bv0.x; v[1] = acc[1] * inv + bv0.y;
    v[2] = acc[2] * inv + bv0.z; v[3] = acc[3] * inv + bv0.w;
    v[4] = acc[4] * inv + bv1.x; v[5] = acc[5] * inv + bv1.y;
    v[6] = acc[6] * inv + bv1.z; v[7] = acc[7] * inv + bv1.w;

    float sum = 0.f;
#pragma unroll
    for (int c = 0; c < 8; ++c) sum += v[c];
#pragma unroll
    for (int off = 1; off < 32; off <<= 1) sum += __shfl_xor(sum, off);
    float mu = sum * (1.0f / 256.0f);
    float d[8], vs = 0.f;
#pragma unroll
    for (int c = 0; c < 8; ++c) { d[c] = v[c] - mu; vs = fmaf(d[c], d[c], vs); }
#pragma unroll
    for (int off = 1; off < 32; off <<= 1) vs += __shfl_xor(vs, off);
    float rstd = rsqrtf(vs * (1.0f / 256.0f) + LN_EPS);
    float4 gv0 = *reinterpret_cast<const float4*>(lng + c0);
    float4 gv1 = *reinterpret_cast<const float4*>(lng + c0 + 4);
    float4 bb0 = *reinterpret_cast<const float4*>(lnb + c0);
    float4 bb1 = *reinterpret_cast<const float4*>(lnb + c0 + 4);
    float g[8] = {gv0.x, gv0.y, gv0.z, gv0.w, gv1.x, gv1.y, gv1.z, gv1.w};
    float bbv[8] = {bb0.x, bb0.y, bb0.z, bb0.w, bb1.x, bb1.y, bb1.z, bb1.w};
    float o[8];
#pragma unroll
    for (int c = 0; c < 8; ++c) {
        float val = fmaf(d[c] * rstd, g[c], bbv[c]);
        o[c] = (val > 0.f) ? val : (__expf(val) - 1.0f);
    }

    if (FUSE_W2) {
        float4 wv0 = *reinterpret_cast<const float4*>(W2 + c0);
        float4 wv1 = *reinterpret_cast<const float4*>(W2 + c0 + 4);
        float wv[8] = {wv0.x, wv0.y, wv0.z, wv0.w, wv1.x, wv1.y, wv1.z, wv1.w};
        float p = 0.f;
#pragma unroll
        for (int c = 0; c < 8; ++c) p = fmaf(o[c], wv[c], p);
#pragma unroll
        for (int off = 1; off < 32; off <<= 1) p += __shfl_xor(p, off);
        if (lh == 0) h2[n] = p;
    } else {
        ushort yo[8];
#pragma unroll
        for (int c = 0; c < 8; ++c) yo[c] = f2bf(o[c]);
        *reinterpret_cast<uint4*>(Y + (size_t)n * 256 + c0) =
            *reinterpret_cast<const uint4*>(yo);
    }
}

// ---------------- layer 2 aggregation (H=1,C=1): 4 nodes/wave ----------------

__global__ __launch_bounds__(256) void k_agg2(
    const int* __restrict__ offs, const int* __restrict__ csr,
    const float* __restrict__ h2,
    const float* __restrict__ as2, const float* __restrict__ ad2,
    const float* __restrict__ b2, float* __restrict__ out, int N)
{
    const int tid = threadIdx.x;
    const int wid = tid >> 6;
    const int lane = tid & 63;
    const int quarter = lane >> 4;
    const int lq = lane & 15;
    const int n = blockIdx.x * 16 + wid * 4 + quarter;
    if (n >= N) return;
    const float asv = as2[0], adv = ad2[0];
    const float tval = adv * h2[n];
    const int beg = offs[n], end = offs[n + 1];

    float m = -1e30f, den = 0.f, num = 0.f;
    for (int i = beg + lq; i < end; i += 16) {
        float hv = h2[csr[i]];
        float e = fmaf(asv, hv, tval);
        e = fmaxf(e, NEG_SLOPE * e);
        float nm = fmaxf(m, e);
        float sc = __expf(m - nm);
        float p = __expf(e - nm);
        den = den * sc + p;
        num = fmaf(num, sc, p * hv);
        m = nm;
    }
#pragma unroll
    for (int o = 1; o < 16; o <<= 1) {
        float m2 = __shfl_xor(m, o);
        float d2 = __shfl_xor(den, o);
        float n2 = __shfl_xor(num, o);
        float nm = fmaxf(m, m2);
        float sA = __expf(m - nm);
        float sB = __expf(m2 - nm);
        den = den * sA + d2 * sB;
        num = num * sA + n2 * sB;
        m = nm;
    }
    if (lq == 0) out[n] = num / den + b2[0];
}

// ---------------- launch ----------------

extern "C" void kernel_launch(void* const* d_in, const int* in_sizes, int n_in,
                              void* d_out, int out_size, void* d_ws, size_t ws_size,
                              hipStream_t stream) {
    const float* x   = (const float*)d_in[0];
    const int*   ei  = (const int*)d_in[1];
    const float* W0  = (const float*)d_in[2];
    const float* as0 = (const float*)d_in[3];
    const float* ad0 = (const float*)d_in[4];
    const float* b0  = (const float*)d_in[5];
    const float* W1  = (const float*)d_in[6];
    const float* as1 = (const float*)d_in[7];
    const float* ad1 = (const float*)d_in[8];
    const float* b1  = (const float*)d_in[9];
    const float* W2  = (const float*)d_in[10];
    const float* as2 = (const float*)d_in[11];
    const float* ad2 = (const float*)d_in[12];
    const float* b2  = (const float*)d_in[13];
    const float* lng = (const float*)d_in[14];
    const float* lnb = (const float*)d_in[15];

    const int N = in_sizes[0] / 64;
    const int E = in_sizes[1] / 2;
    const int TOT = E + N;
    const int NB = (N + 1023) / 1024;

    char* w = (char*)d_ws;
    auto alloc = [&](size_t bytes) -> void* {
        void* p = (void*)w;
        w += (bytes + 255) & ~(size_t)255;
        return p;
    };
    int*    cnt    = (int*)alloc(sizeof(int) * N);
    int*    offs   = (int*)alloc(sizeof(int) * (N + 1));
    int*    cursor = (int*)alloc(sizeof(int) * N);
    int*    csr    = (int*)alloc(sizeof(int) * TOT);
    int*    bsum   = (int*)alloc(sizeof(int) * (NB + 1));
    int*    bcarry = (int*)alloc(sizeof(int) * (NB + 1));
    float*  sbuf   = (float*)alloc(sizeof(float) * N * 4);
    float*  tbuf   = (float*)alloc(sizeof(float) * N * 4);
    uint*   gkeys  = (uint*)alloc(sizeof(uint) * 8);       // [0..3] L0, [4..7] L1
    ushort* Xb     = (ushort*)alloc(sizeof(ushort) * (size_t)N * 64);
    ushort* Wt0    = (ushort*)alloc(sizeof(ushort) * 256 * 64);
    ushort* Wt1    = (ushort*)alloc(sizeof(ushort) * 256 * 256);
    ushort* hbf    = (ushort*)alloc(sizeof(ushort) * (size_t)N * 256);
    ushort* Yb     = (ushort*)alloc(sizeof(ushort) * (size_t)N * 256);
    float*  h2     = (float*)alloc(sizeof(float) * N);
    float*  out    = (float*)d_out;

    // zero-init histogram + gmax keys
    hipMemsetAsync(cnt, 0, sizeof(int) * N, stream);
    hipMemsetAsync(gkeys, 0, sizeof(uint) * 8, stream);
    const int cvt_tot = N * 8 + 64 * 256 + 256 * 256;
    k_cvt_all<<<(cvt_tot + 255) / 256, 256, 0, stream>>>(x, W0, W1, Xb, Wt0, Wt1, N);

    // CSR build
    k_hist<<<(TOT + 255) / 256, 256, 0, stream>>>(ei, E, N, cnt);
    k_scan1<<<NB, 1024, 0, stream>>>(cnt, offs, bsum, N);
    k_scan2<<<1, 1024, 0, stream>>>(bsum, bcarry, NB);
    k_scan3<<<(N + 255) / 256, 256, 0, stream>>>(offs, bcarry, cursor, N);
    k_scatter<<<(TOT + 255) / 256, 256, 0, stream>>>(ei, E, N, cursor, csr);

    // GEMM grid: 8 xcds x cpx chunks x 4 slices; each block does rbpc row-blocks
    const int nrb = (N + 63) / 64;
    const int cpx = 25;
    const int chunks = 8 * cpx;
    const int rbpc = (nrb + chunks - 1) / chunks;
    const int gemm_grid = chunks * 4;
    const int node_grid8 = (N + 7) / 8;
    const int node_grid16 = (N + 15) / 16;

    // layer 0
    k_gemm_mfma<64><<<gemm_grid, 256, 0, stream>>>(Xb, Wt0, as0, ad0, hbf, sbuf, tbuf,
                                                   gkeys, N, nrb, cpx, rbpc);
    k_agg_ln_elu<false><<<node_grid8, 256, 0, stream>>>(offs, csr, sbuf, tbuf, hbf, gkeys,
                                                        b0, lng, lnb, Yb, nullptr, nullptr, N);
    // layer 1 (+ fused 256->1 projection)
    k_gemm_mfma<256><<<gemm_grid, 256, 0, stream>>>(Yb, Wt1, as1, ad1, hbf, sbuf, tbuf,
                                                    gkeys + 4, N, nrb, cpx, rbpc);
    k_agg_ln_elu<true><<<node_grid8, 256, 0, stream>>>(offs, csr, sbuf, tbuf, hbf, gkeys + 4,
                                                       b1, lng, lnb, nullptr, W2, h2, N);
    // layer 2
    k_agg2<<<node_grid16, 256, 0, stream>>>(offs, csr, h2, as2, ad2, b2, out, N);
}